// Round 3
// baseline (267.003 us; speedup 1.0000x reference)
//
#include <hip/hip_runtime.h>
#include <math.h>

// ---------------------------------------------------------------------------
// HROMAttention: x(4,2048,512) -> QKV(+bias) -> RoPE -> MHA(8 heads, d=64)
//                -> proj(+bias). bf16 MFMA 16x16x32, fp32 accum.
// Round 3:
//  - attn: no K/V LDS staging (global b128 frags, L2-resident), 2-way split-K
//    (2 waves/block, 16 waves/CU), mask folded into MFMA C-init, row-sum l via
//    ones-A-frag MFMA, cvt_pk_bf16 packing.
//  - qkv/proj: operand-swapped MFMA for Q/K/proj so lanes hold consecutive
//    output-d -> vectorized RoPE + ushort4/float4 stores (was 64 scalar/lane).
// ws layout (bytes) — identical to round 2:
//   [0)         xb     bf16 8192x512     8388608
//   [8388608)   wqb    bf16 1536x512     1572864
//   [9961472)   wpb    bf16  512x512      524288
//   [10485760)  cosT   f32  2048x32       262144
//   [10747904)  sinT   f32  2048x32       262144
//   [11010048)  Qb     bf16 (b,h,t,d)    8388608   (pre-scaled by 0.125*log2e)
//   [19398656)  Kb     bf16 (b,h,t,d)    8388608
//   [27787264)  Vtb    bf16 (b,h,d,t)    8388608
//   [36175872)  attnb  bf16 8192x512     8388608
// ---------------------------------------------------------------------------

typedef __attribute__((ext_vector_type(8))) short bf16x8;
typedef __attribute__((ext_vector_type(4))) float floatx4;

#define LOG2E 1.44269504088896f

__device__ __forceinline__ unsigned short f2bf(float f) {
  unsigned int u = __float_as_uint(f);
  u += 0x7fffu + ((u >> 16) & 1u);   // round-to-nearest-even
  return (unsigned short)(u >> 16);
}

#if defined(__has_builtin)
#if __has_builtin(__builtin_amdgcn_cvt_pk_bf16_f32)
#define HAVE_PK_BF16 1
#endif
#endif

// pack two fp32 -> two bf16 in one uint (low = a)
__device__ __forceinline__ unsigned int f2bf2(float a, float b) {
#ifdef HAVE_PK_BF16
  auto v = __builtin_amdgcn_cvt_pk_bf16_f32(a, b);
  union { decltype(v) x; unsigned int u; } c;
  c.x = v;
  return c.u;
#else
  return (unsigned int)f2bf(a) | ((unsigned int)f2bf(b) << 16);
#endif
}

__device__ __forceinline__ void gld_lds16(unsigned short* lds, const unsigned short* g) {
  __builtin_amdgcn_global_load_lds(
      (const __attribute__((address_space(1))) unsigned int*)g,
      (__attribute__((address_space(3))) unsigned int*)lds, 16, 0, 0);
}

// ---------------------------------------------------------------------------
// prep: bf16 conversions + RoPE cos/sin table (fp64 trig for accuracy)
// ---------------------------------------------------------------------------
__global__ __launch_bounds__(256) void prep_kernel(
    const float* __restrict__ x, const float* __restrict__ wq, const float* __restrict__ wp,
    unsigned short* __restrict__ xb, unsigned short* __restrict__ wqb,
    unsigned short* __restrict__ wpb, float* __restrict__ cosT, float* __restrict__ sinT) {
  int i = blockIdx.x * 256 + threadIdx.x;
  if (i < 4194304) {
    xb[i] = f2bf(x[i]);
  } else if (i < 4980736) {
    int j = i - 4194304; wqb[j] = f2bf(wq[j]);
  } else if (i < 5242880) {
    int j = i - 4980736; wpb[j] = f2bf(wp[j]);
  } else if (i < 5308416) {
    int j = i - 5242880;
    int t = j >> 5, f = j & 31;
    double fr = (double)t * pow(10000.0, -(double)f / 32.0);
    cosT[j] = (float)cos(fr);
    sinT[j] = (float)sin(fr);
  }
}

// ---------------------------------------------------------------------------
// QKV GEMM: 128x128 tile, BK=32, 4 waves each 64x64.
// Q/K blocks (blockIdx.y<8): swapped operands -> C[w-col][t]; lanes hold 4
// consecutive d -> vectorized RoPE + ushort4 stores to (b,h,t,d).
// V blocks: normal orientation -> lanes hold 4 consecutive t -> ushort4
// stores to transposed (b,h,d,t).
// ---------------------------------------------------------------------------
__global__ __launch_bounds__(256) void qkv_kernel(
    const unsigned short* __restrict__ xb, const unsigned short* __restrict__ wqb,
    const float* __restrict__ qkv_b, const float* __restrict__ cosT,
    const float* __restrict__ sinT, unsigned short* __restrict__ Qb,
    unsigned short* __restrict__ Kb, unsigned short* __restrict__ Vtb) {
  __shared__ __align__(16) unsigned short As[128 * 32];
  __shared__ __align__(16) unsigned short Bs[128 * 32];
  const int tid = threadIdx.x;
  const int wave = tid >> 6, lane = tid & 63, ln = lane & 15, quad = lane >> 4;
  const int m0 = blockIdx.x * 128, n0 = blockIdx.y * 128;
  const int wr = (wave >> 1) * 64, wc = (wave & 1) * 64;
  const bool isV = (blockIdx.y >= 8);

  floatx4 acc[4][4];
#pragma unroll
  for (int i = 0; i < 4; ++i)
#pragma unroll
    for (int j = 0; j < 4; ++j) acc[i][j] = (floatx4){0.f, 0.f, 0.f, 0.f};

  const int c0 = tid, c1 = tid + 256;
  const int ar0 = c0 >> 2, ak0 = (c0 & 3) * 8;
  const int ar1 = c1 >> 2, ak1 = (c1 & 3) * 8;

  for (int k0 = 0; k0 < 512; k0 += 32) {
    __syncthreads();
    gld_lds16(As + c0 * 8, xb + (size_t)(m0 + ar0) * 512 + k0 + ak0);
    gld_lds16(As + c1 * 8, xb + (size_t)(m0 + ar1) * 512 + k0 + ak1);
    gld_lds16(Bs + c0 * 8, wqb + (size_t)(n0 + ar0) * 512 + k0 + ak0);
    gld_lds16(Bs + c1 * 8, wqb + (size_t)(n0 + ar1) * 512 + k0 + ak1);
    __syncthreads();
    bf16x8 af[4], bfb[4];
#pragma unroll
    for (int mi = 0; mi < 4; ++mi)
      af[mi] = *(const bf16x8*)(As + (wr + mi * 16 + ln) * 32 + quad * 8);
#pragma unroll
    for (int ni = 0; ni < 4; ++ni)
      bfb[ni] = *(const bf16x8*)(Bs + (wc + ni * 16 + ln) * 32 + quad * 8);
    if (isV) {
#pragma unroll
      for (int mi = 0; mi < 4; ++mi)
#pragma unroll
        for (int ni = 0; ni < 4; ++ni)
          acc[mi][ni] = __builtin_amdgcn_mfma_f32_16x16x32_bf16(af[mi], bfb[ni], acc[mi][ni], 0, 0, 0);
    } else {
      // swapped: C[m=w-col][n=t]
#pragma unroll
      for (int mi = 0; mi < 4; ++mi)
#pragma unroll
        for (int ni = 0; ni < 4; ++ni)
          acc[mi][ni] = __builtin_amdgcn_mfma_f32_16x16x32_bf16(bfb[mi], af[ni], acc[mi][ni], 0, 0, 0);
    }
  }

  const int colbase = n0 + wc;                    // multiple of 64 -> one (mat, head)
  const int mat = colbase >> 9;                   // 0=q 1=k 2=v
  const int h = (colbase & 511) >> 6;

  if (isV) {
    // V: lanes hold 4 consecutive t at fixed d -> (b,h,d,t)
    float bias[4];
#pragma unroll
    for (int ni = 0; ni < 4; ++ni) bias[ni] = qkv_b[colbase + ni * 16 + ln];
#pragma unroll
    for (int mi = 0; mi < 4; ++mi) {
      int row0 = m0 + wr + mi * 16 + quad * 4;
      int bidx = row0 >> 11, t = row0 & 2047;
#pragma unroll
      for (int ni = 0; ni < 4; ++ni) {
        int d = ni * 16 + ln;
        unsigned int u0 = f2bf2(acc[mi][ni][0] + bias[ni], acc[mi][ni][1] + bias[ni]);
        unsigned int u1 = f2bf2(acc[mi][ni][2] + bias[ni], acc[mi][ni][3] + bias[ni]);
        *(uint2*)(Vtb + ((size_t)(bidx * 8 + h) * 64 + d) * 2048 + t) = make_uint2(u0, u1);
      }
    }
  } else {
    // Q/K (swapped C): lane holds 4 consecutive d; RoPE pair (d, d+32) = (mi, mi+2)
    unsigned short* dst = (mat == 0) ? Qb : Kb;
    const float sc = (mat == 0) ? 0.125f * LOG2E : 1.0f;   // fold scale + log2e into Q
    float4 blo[2], bhi[2];
#pragma unroll
    for (int mi = 0; mi < 2; ++mi) {
      blo[mi] = *(const float4*)(qkv_b + colbase + mi * 16 + quad * 4);
      bhi[mi] = *(const float4*)(qkv_b + colbase + 32 + mi * 16 + quad * 4);
    }
#pragma unroll
    for (int ni = 0; ni < 4; ++ni) {
      int row = m0 + wr + ni * 16 + ln;
      int bidx = row >> 11, t = row & 2047;
      unsigned short* tb = dst + ((size_t)(bidx * 8 + h) * 2048 + t) * 64;
#pragma unroll
      for (int mi = 0; mi < 2; ++mi) {
        int dbase = mi * 16 + quad * 4;
        float4 c4 = *(const float4*)(cosT + t * 32 + dbase);
        float4 s4 = *(const float4*)(sinT + t * 32 + dbase);
        float xl0 = acc[mi][ni][0] + blo[mi].x, xh0 = acc[mi + 2][ni][0] + bhi[mi].x;
        float xl1 = acc[mi][ni][1] + blo[mi].y, xh1 = acc[mi + 2][ni][1] + bhi[mi].y;
        float xl2 = acc[mi][ni][2] + blo[mi].z, xh2 = acc[mi + 2][ni][2] + bhi[mi].z;
        float xl3 = acc[mi][ni][3] + blo[mi].w, xh3 = acc[mi + 2][ni][3] + bhi[mi].w;
        unsigned int lo01 = f2bf2((xl0 * c4.x - xh0 * s4.x) * sc, (xl1 * c4.y - xh1 * s4.y) * sc);
        unsigned int lo23 = f2bf2((xl2 * c4.z - xh2 * s4.z) * sc, (xl3 * c4.w - xh3 * s4.w) * sc);
        unsigned int hi01 = f2bf2((xh0 * c4.x + xl0 * s4.x) * sc, (xh1 * c4.y + xl1 * s4.y) * sc);
        unsigned int hi23 = f2bf2((xh2 * c4.z + xl2 * s4.z) * sc, (xh3 * c4.w + xl3 * s4.w) * sc);
        *(uint2*)(tb + dbase) = make_uint2(lo01, lo23);
        *(uint2*)(tb + 32 + dbase) = make_uint2(hi01, hi23);
      }
    }
  }
}

// ---------------------------------------------------------------------------
// Flash attention, transposed (S^T = K·Q^T), split-K:
// block = 128 thr = 2 waves, both on the same 32 q of one (b,h); wave w covers
// k in [w*1024, (w+1)*1024). K/V frags read directly from global (L2-resident,
// coalesced b128: 16 rows x 128 B). Mask folded into MFMA C-init. Row-sum l
// via ones-A MFMA (all acc elements equal -> no shuffles). End: wave0 dumps
// partials (m, l, O) to LDS, wave1 merges + stores.
// ---------------------------------------------------------------------------
__global__ __launch_bounds__(128, 4) void attn_kernel(
    const unsigned short* __restrict__ Qb, const unsigned short* __restrict__ Kb,
    const unsigned short* __restrict__ Vtb, const float* __restrict__ mask,
    unsigned short* __restrict__ attnb) {
  __shared__ __align__(16) unsigned short Ps[2 * 32 * 72];  // per-wave (q, t_k)
  __shared__ __align__(16) float Om[8 * 64 * 4];            // wave0 O partial
  __shared__ float Ml[4 * 64];                              // wave0 m, l

  const int tid = threadIdx.x;
  const int wave = tid >> 6, lane = tid & 63, ln = lane & 15, quad = lane >> 4;
  const int bh = blockIdx.y;
  const int b = bh >> 3, h = bh & 7;
  const int q0 = blockIdx.x * 32;
  const int kbeg = wave * 1024;

  const unsigned short* Qhead = Qb + (size_t)bh * 2048 * 64;
  const unsigned short* Khead = Kb + (size_t)bh * 2048 * 64;
  const unsigned short* Vhead = Vtb + (size_t)bh * 64 * 2048;
  unsigned short* Pw = Ps + wave * 32 * 72;

  // Q B-frags: B[n=q][k=d]
  bf16x8 qf[2][2];
#pragma unroll
  for (int ni2 = 0; ni2 < 2; ++ni2)
#pragma unroll
    for (int ks = 0; ks < 2; ++ks)
      qf[ni2][ks] = *(const bf16x8*)(Qhead + (size_t)(q0 + ni2 * 16 + ln) * 64 + ks * 32 + quad * 8);

  // ones A-frag for row-sum l
  bf16x8 ones;
#pragma unroll
  for (int j = 0; j < 8; ++j) ones[j] = (short)0x3F80;

  floatx4 o[4][2];   // O^T: [d-tile][q-tile]
#pragma unroll
  for (int mi2 = 0; mi2 < 4; ++mi2)
#pragma unroll
    for (int ni2 = 0; ni2 < 2; ++ni2) o[mi2][ni2] = (floatx4){0.f, 0.f, 0.f, 0.f};
  floatx4 o5[2] = {(floatx4){0.f, 0.f, 0.f, 0.f}, (floatx4){0.f, 0.f, 0.f, 0.f}};
  float mrun[2] = {-INFINITY, -INFINITY};

  for (int k0 = kbeg; k0 < kbeg + 1024; k0 += 64) {
    // mask -> C-init (log2 domain)
    floatx4 cini[4];
#pragma unroll
    for (int mi = 0; mi < 4; ++mi) {
      float4 mv = *(const float4*)(mask + b * 2048 + k0 + mi * 16 + quad * 4);
      cini[mi] = (floatx4){mv.x * LOG2E, mv.y * LOG2E, mv.z * LOG2E, mv.w * LOG2E};
    }
    // S^T = K·Q^T, K frags straight from global
    floatx4 sm[4][2];
#pragma unroll
    for (int mi = 0; mi < 4; ++mi) {
      bf16x8 kf0 = *(const bf16x8*)(Khead + (size_t)(k0 + mi * 16 + ln) * 64 + quad * 8);
      bf16x8 kf1 = *(const bf16x8*)(Khead + (size_t)(k0 + mi * 16 + ln) * 64 + 32 + quad * 8);
#pragma unroll
      for (int ni2 = 0; ni2 < 2; ++ni2) {
        floatx4 a = cini[mi];
        a = __builtin_amdgcn_mfma_f32_16x16x32_bf16(kf0, qf[ni2][0], a, 0, 0, 0);
        a = __builtin_amdgcn_mfma_f32_16x16x32_bf16(kf1, qf[ni2][1], a, 0, 0, 0);
        sm[mi][ni2] = a;
      }
    }
    // online softmax (per lane one q-col; cross-quad via 2 shuffles)
    float alpha[2];
#pragma unroll
    for (int ni2 = 0; ni2 < 2; ++ni2) {
      float vmax = fmaxf(fmaxf(sm[0][ni2][0], sm[0][ni2][1]), fmaxf(sm[0][ni2][2], sm[0][ni2][3]));
#pragma unroll
      for (int mi = 1; mi < 4; ++mi) {
        vmax = fmaxf(vmax, fmaxf(fmaxf(sm[mi][ni2][0], sm[mi][ni2][1]),
                                 fmaxf(sm[mi][ni2][2], sm[mi][ni2][3])));
      }
      vmax = fmaxf(vmax, __shfl_xor(vmax, 16));
      vmax = fmaxf(vmax, __shfl_xor(vmax, 32));
      float nm = fmaxf(mrun[ni2], vmax);
      alpha[ni2] = exp2f(mrun[ni2] - nm);
      mrun[ni2] = nm;
    }
    // rescale O and l
#pragma unroll
    for (int mi2 = 0; mi2 < 4; ++mi2)
#pragma unroll
      for (int ni2 = 0; ni2 < 2; ++ni2) {
        o[mi2][ni2][0] *= alpha[ni2]; o[mi2][ni2][1] *= alpha[ni2];
        o[mi2][ni2][2] *= alpha[ni2]; o[mi2][ni2][3] *= alpha[ni2];
      }
#pragma unroll
    for (int ni2 = 0; ni2 < 2; ++ni2) {
      o5[ni2][0] *= alpha[ni2]; o5[ni2][1] *= alpha[ni2];
      o5[ni2][2] *= alpha[ni2]; o5[ni2][3] *= alpha[ni2];
    }
    // p = exp2(s - m), pack to bf16, P^T -> per-wave LDS (no barrier needed)
#pragma unroll
    for (int mi = 0; mi < 4; ++mi)
#pragma unroll
      for (int ni2 = 0; ni2 < 2; ++ni2) {
        unsigned int u0 = f2bf2(exp2f(sm[mi][ni2][0] - mrun[ni2]), exp2f(sm[mi][ni2][1] - mrun[ni2]));
        unsigned int u1 = f2bf2(exp2f(sm[mi][ni2][2] - mrun[ni2]), exp2f(sm[mi][ni2][3] - mrun[ni2]));
        *(uint2*)(Pw + (ni2 * 16 + ln) * 72 + mi * 16 + quad * 4) = make_uint2(u0, u1);
      }
    // O^T += V^T·P (V frags from global) ; l += ones·P
#pragma unroll
    for (int ks = 0; ks < 2; ++ks) {
      bf16x8 pb[2];
#pragma unroll
      for (int ni2 = 0; ni2 < 2; ++ni2)
        pb[ni2] = *(const bf16x8*)(Pw + (ni2 * 16 + ln) * 72 + ks * 32 + quad * 8);
#pragma unroll
      for (int mi2 = 0; mi2 < 4; ++mi2) {
        bf16x8 vf = *(const bf16x8*)(Vhead + (size_t)(mi2 * 16 + ln) * 2048 + k0 + ks * 32 + quad * 8);
#pragma unroll
        for (int ni2 = 0; ni2 < 2; ++ni2)
          o[mi2][ni2] = __builtin_amdgcn_mfma_f32_16x16x32_bf16(vf, pb[ni2], o[mi2][ni2], 0, 0, 0);
      }
#pragma unroll
      for (int ni2 = 0; ni2 < 2; ++ni2)
        o5[ni2] = __builtin_amdgcn_mfma_f32_16x16x32_bf16(ones, pb[ni2], o5[ni2], 0, 0, 0);
    }
  }

  // ---- split-K merge: wave0 -> LDS, wave1 combines + stores ----
  if (wave == 0) {
#pragma unroll
    for (int mi2 = 0; mi2 < 4; ++mi2)
#pragma unroll
      for (int ni2 = 0; ni2 < 2; ++ni2)
        *(floatx4*)(Om + ((mi2 * 2 + ni2) * 64 + lane) * 4) = o[mi2][ni2];
#pragma unroll
    for (int ni2 = 0; ni2 < 2; ++ni2) {
      Ml[ni2 * 64 + lane] = mrun[ni2];
      Ml[128 + ni2 * 64 + lane] = o5[ni2][0];
    }
  }
  __syncthreads();
  if (wave == 1) {
#pragma unroll
    for (int ni2 = 0; ni2 < 2; ++ni2) {
      float m0s = Ml[ni2 * 64 + lane];
      float l0s = Ml[128 + ni2 * 64 + lane];
      float M = fmaxf(m0s, mrun[ni2]);
      float c0 = exp2f(m0s - M);
      float c1 = exp2f(mrun[ni2] - M);
      float inv = 1.f / (l0s * c0 + o5[ni2][0] * c1);
      float ic0 = c0 * inv, ic1 = c1 * inv;
      int t = q0 + ni2 * 16 + ln;
      size_t base = ((size_t)b * 2048 + t) * 512 + h * 64;
#pragma unroll
      for (int mi2 = 0; mi2 < 4; ++mi2) {
        floatx4 p0 = *(const floatx4*)(Om + ((mi2 * 2 + ni2) * 64 + lane) * 4);
        unsigned int u0 = f2bf2(p0[0] * ic0 + o[mi2][ni2][0] * ic1,
                                p0[1] * ic0 + o[mi2][ni2][1] * ic1);
        unsigned int u1 = f2bf2(p0[2] * ic0 + o[mi2][ni2][2] * ic1,
                                p0[3] * ic0 + o[mi2][ni2][3] * ic1);
        *(uint2*)(attnb + base + mi2 * 16 + quad * 4) = make_uint2(u0, u1);
      }
    }
  }
}

// ---------------------------------------------------------------------------
// proj GEMM (swapped operands): C[w-col][t] so lanes hold 4 consecutive output
// cols -> float4 stores. attnb(8192x512) @ wpb(512x512)^T + bias -> out fp32.
// ---------------------------------------------------------------------------
__global__ __launch_bounds__(256) void proj_kernel(
    const unsigned short* __restrict__ ab, const unsigned short* __restrict__ wpb,
    const float* __restrict__ proj_b, float* __restrict__ out) {
  __shared__ __align__(16) unsigned short As[128 * 32];
  __shared__ __align__(16) unsigned short Bs[128 * 32];
  const int tid = threadIdx.x;
  const int wave = tid >> 6, lane = tid & 63, ln = lane & 15, quad = lane >> 4;
  const int m0 = blockIdx.x * 128, n0 = blockIdx.y * 128;
  const int wr = (wave >> 1) * 64, wc = (wave & 1) * 64;

  floatx4 acc[4][4];
#pragma unroll
  for (int i = 0; i < 4; ++i)
#pragma unroll
    for (int j = 0; j < 4; ++j) acc[i][j] = (floatx4){0.f, 0.f, 0.f, 0.f};

  const int c0 = tid, c1 = tid + 256;
  const int ar0 = c0 >> 2, ak0 = (c0 & 3) * 8;
  const int ar1 = c1 >> 2, ak1 = (c1 & 3) * 8;

  for (int k0 = 0; k0 < 512; k0 += 32) {
    __syncthreads();
    gld_lds16(As + c0 * 8, ab + (size_t)(m0 + ar0) * 512 + k0 + ak0);
    gld_lds16(As + c1 * 8, ab + (size_t)(m0 + ar1) * 512 + k0 + ak1);
    gld_lds16(Bs + c0 * 8, wpb + (size_t)(n0 + ar0) * 512 + k0 + ak0);
    gld_lds16(Bs + c1 * 8, wpb + (size_t)(n0 + ar1) * 512 + k0 + ak1);
    __syncthreads();
    bf16x8 af[4], bfb[4];
#pragma unroll
    for (int mi = 0; mi < 4; ++mi)
      af[mi] = *(const bf16x8*)(As + (wr + mi * 16 + ln) * 32 + quad * 8);
#pragma unroll
    for (int ni = 0; ni < 4; ++ni)
      bfb[ni] = *(const bf16x8*)(Bs + (wc + ni * 16 + ln) * 32 + quad * 8);
#pragma unroll
    for (int mi = 0; mi < 4; ++mi)
#pragma unroll
      for (int ni = 0; ni < 4; ++ni)
        acc[mi][ni] = __builtin_amdgcn_mfma_f32_16x16x32_bf16(bfb[mi], af[ni], acc[mi][ni], 0, 0, 0);
  }

  float4 bias4[4];
#pragma unroll
  for (int mi = 0; mi < 4; ++mi)
    bias4[mi] = *(const float4*)(proj_b + n0 + wc + mi * 16 + quad * 4);
#pragma unroll
  for (int ni = 0; ni < 4; ++ni) {
    int t = m0 + wr + ni * 16 + ln;
#pragma unroll
    for (int mi = 0; mi < 4; ++mi) {
      int col = n0 + wc + mi * 16 + quad * 4;
      float4 st;
      st.x = acc[mi][ni][0] + bias4[mi].x;
      st.y = acc[mi][ni][1] + bias4[mi].y;
      st.z = acc[mi][ni][2] + bias4[mi].z;
      st.w = acc[mi][ni][3] + bias4[mi].w;
      *(float4*)(out + (size_t)t * 512 + col) = st;
    }
  }
}

// ---------------------------------------------------------------------------
extern "C" void kernel_launch(void* const* d_in, const int* in_sizes, int n_in,
                              void* d_out, int out_size, void* d_ws, size_t ws_size,
                              hipStream_t stream) {
  const float* x      = (const float*)d_in[0];
  const float* mask   = (const float*)d_in[1];
  const float* qkv_w  = (const float*)d_in[2];
  const float* qkv_b  = (const float*)d_in[3];
  const float* proj_w = (const float*)d_in[4];
  const float* proj_b = (const float*)d_in[5];
  float* out = (float*)d_out;

  char* ws = (char*)d_ws;
  unsigned short* xb   = (unsigned short*)(ws);
  unsigned short* wqb  = (unsigned short*)(ws + 8388608);
  unsigned short* wpb  = (unsigned short*)(ws + 9961472);
  float* cosT          = (float*)(ws + 10485760);
  float* sinT          = (float*)(ws + 10747904);
  unsigned short* Qb   = (unsigned short*)(ws + 11010048);
  unsigned short* Kb   = (unsigned short*)(ws + 19398656);
  unsigned short* Vtb  = (unsigned short*)(ws + 27787264);
  unsigned short* attnb= (unsigned short*)(ws + 36175872);

  prep_kernel<<<20736, 256, 0, stream>>>(x, qkv_w, proj_w, xb, wqb, wpb, cosT, sinT);
  dim3 g1(64, 12);
  qkv_kernel<<<g1, 256, 0, stream>>>(xb, wqb, qkv_b, cosT, sinT, Qb, Kb, Vtb);
  dim3 g2(64, 32);
  attn_kernel<<<g2, 128, 0, stream>>>(Qb, Kb, Vtb, mask, attnb);
  dim3 g3(64, 4);
  proj_kernel<<<g3, 256, 0, stream>>>(attnb, wpb, proj_b, out);
}